// Round 8
// baseline (401.501 us; speedup 1.0000x reference)
//
#include <hip/hip_runtime.h>
#include <math.h>

#define NB 32              // batches per 512-thread block
#define NSLAB 128          // slab = ONE W k-row (8 KB)
#define UNI_F 10240        // 40 KB union: 4x8KB slab bufs (first 8192 f) / transpose scratch

// R8: counted-vmcnt 4-buffer pipeline (T3/T4, m201 pattern) + SALU occupancy
// masks. R7 was barrier-drain-bound (~45% of cycles: 64 x __syncthreads each
// draining vmcnt(0) on just-issued staging loads).
//  - slab = 1 k-row, NBUF=4, prefetch distance 3. Per iter:
//    s_waitcnt vmcnt(2) lgkmcnt(0); s_barrier; issue stage(s+3); gather(s).
//    vmcnt never drains to 0 in the main loop. Overwrite target buf[(s+3)&3]
//    = buf[(s-1)&3] was last gathered pre-barrier (lgkmcnt(0) before barrier
//    guarantees all waves' reads completed) -> race-free.
//  - occupancy test: per-wave 128-bit masks in SGPRs via __ballot (2 loads +
//    2 ballots per batch, L2-hot re-read). Gather offsets never needed the
//    sorted walk -> all per-iter list ds_reads (48K cy/CU) eliminated.
//  - gather: full-wave, lane=(row 0..31, half 0..1), 2 b128/occupied k =
//    hw minimum (8 lanes/bank-quad, different rows: 8-way serialization IS
//    the 1024B/128B floor; PMC counts it as conflict - ignore).
//  - transpose to LU layout via per-wave scratch aliased over dead bufs;
//    LU: 8-lane implicit partial pivot (lexicographic tie-break) unchanged.
// k-sum ascending -> bitwise-identical to previous rounds.

typedef float f32x2 __attribute__((ext_vector_type(2)));
typedef float f32x4 __attribute__((ext_vector_type(4)));

#define GLD_LDS16(gp, lp) __builtin_amdgcn_global_load_lds( \
    (const __attribute__((address_space(1))) void*)(gp),    \
    (__attribute__((address_space(3))) void*)(lp), 16, 0, 0)

// acc (f32x2) += half of a b128 load, one packed add (IEEE-identical)
#define PKADD(acc, half) asm("v_pk_add_f32 %0, %0, %1" : "+v"(acc) : "v"(half))

__global__ __launch_bounds__(512, 4) void backflow_kernel(
    const int* __restrict__ nocc,   // (B,128) int32 0/1
    const float* __restrict__ W,    // (128,2048) f32 row-major
    float* __restrict__ out,        // planar: [B re][B im]
    int B)
{
    __shared__ __align__(16) float uni[UNI_F];   // slab bufs, later scratch
    __shared__ int lists[NB][33];

    const int tid = threadIdx.x;

    // ---------------- phase 1: occupancy -> row lists (for gather offsets) ----
    {
        const int bib1 = tid >> 4;                 // 0..31
        const int l16  = tid & 15;
        int batch1 = blockIdx.x * NB + bib1;
        if (batch1 >= B) batch1 = B - 1;
        const int4* np = reinterpret_cast<const int4*>(nocc + (size_t)batch1 * 128 + l16 * 8);
        int4 v0 = np[0];
        int4 v1 = np[1];
        unsigned nib = 0;
        nib |= (v0.x != 0) ? 1u   : 0u;
        nib |= (v0.y != 0) ? 2u   : 0u;
        nib |= (v0.z != 0) ? 4u   : 0u;
        nib |= (v0.w != 0) ? 8u   : 0u;
        nib |= (v1.x != 0) ? 16u  : 0u;
        nib |= (v1.y != 0) ? 32u  : 0u;
        nib |= (v1.z != 0) ? 64u  : 0u;
        nib |= (v1.w != 0) ? 128u : 0u;
        const int cnt = __popc(nib);
        int incl = cnt;
        const int seg = l16 & 7;
        #pragma unroll
        for (int d = 1; d < 8; d <<= 1) {
            int t = __shfl_up(incl, d, 8);
            if (seg >= d) incl += t;
        }
        int pos = ((l16 >> 3) << 4) + (incl - cnt);
        const int k0 = l16 * 8;
        #pragma unroll
        for (int b = 0; b < 8; b++) {
            if (nib & (1u << b)) lists[bib1][pos++] = k0 + b;
        }
    }
    __syncthreads();

    // ---------------- ids ----------------
    const int lane = tid & 63;
    const int wv   = __builtin_amdgcn_readfirstlane(tid >> 6);  // 0..7
    const int wb0  = wv << 2;            // first batch-in-wave

    const int rowidx = lane >> 1;        // owned A-row 0..31
    const int h      = lane & 1;         // 8-float half of the 16-col row
    const int m2     = rowidx >> 4;      // spin of owned row
    const int rot    = rowidx & 1;       // chunk-parity rotation key

    // ---------------- per-wave occupancy masks in SGPRs ----------------
    unsigned long long mlo[4], mhi[4];
    #pragma unroll
    for (int b = 0; b < 4; b++) {
        int gb = blockIdx.x * NB + wb0 + b;
        if (gb >= B) gb = B - 1;
        const int* npb = nocc + (size_t)gb * 128;
        const int vlo = npb[lane];
        const int vhi = npb[64 + lane];
        mlo[b] = __ballot(vlo != 0);     // bit k   = occupancy of k (k<64)
        mhi[b] = __ballot(vhi != 0);     // bit k-64 (k>=64)
    }

    // ---------------- gather offsets (bytes within one staged k-row) --------
    int offs[4][2];
    #pragma unroll
    for (int b = 0; b < 4; b++) {
        const int ro = lists[wb0 + b][rowidx] - (m2 << 6);   // 0..63
        offs[b][0] = (ro << 7) + (m2 << 6) + (h << 5) + ((0 ^ rot) << 4);
        offs[b][1] = (ro << 7) + (m2 << 6) + (h << 5) + ((1 ^ rot) << 4);
    }

    f32x2 acc[4][4] = {};   // [batch][2*slot+e]; slot c = physical chunk c^rot

    // ---------------- staging prologue ----------------
    const int col_l = (wv << 8) + (lane << 2);       // float idx within k-row
    const char* gp = (const char*)(W + col_l);
    asm volatile("s_waitcnt vmcnt(0)" ::: "memory"); // ballot loads drained
    __builtin_amdgcn_sched_barrier(0);
    #pragma unroll
    for (int i = 0; i < 3; i++) {                    // stage slabs 0,1,2
        GLD_LDS16(gp, (char*)uni + i * 8192 + (wv << 10));
        gp += 8192;
    }

    // ---------------- main loop: counted-vmcnt 4-buffer pipeline ----------
    #pragma unroll 1
    for (int s = 0; s < NSLAB; s++) {
        if (s < NSLAB - 2)      asm volatile("s_waitcnt vmcnt(2) lgkmcnt(0)" ::: "memory");
        else if (s == NSLAB - 2) asm volatile("s_waitcnt vmcnt(1) lgkmcnt(0)" ::: "memory");
        else                     asm volatile("s_waitcnt vmcnt(0) lgkmcnt(0)" ::: "memory");
        __builtin_amdgcn_s_barrier();                // slab s resident everywhere
        __builtin_amdgcn_sched_barrier(0);
        if (s < NSLAB - 3) {                         // stage slab s+3
            GLD_LDS16(gp, (char*)uni + ((s + 3) & 3) * 8192 + (wv << 10));
            gp += 8192;
        }
        const char* kp = (const char*)uni + ((s & 3) << 13);
        #pragma unroll
        for (int b = 0; b < 4; b++) {
            const bool occ = (((s < 64 ? (mlo[b] >> s) : (mhi[b] >> (s - 64))) & 1ull) != 0);
            if (occ) {
                const f32x4 v0 = *reinterpret_cast<const f32x4*>(kp + offs[b][0]);
                const f32x4 v1 = *reinterpret_cast<const f32x4*>(kp + offs[b][1]);
                PKADD(acc[b][0], v0.lo); PKADD(acc[b][1], v0.hi);
                PKADD(acc[b][2], v1.lo); PKADD(acc[b][3], v1.hi);
            }
        }
    }
    __syncthreads();   // all gathers done -> bufs dead, safe to reuse as scratch

    // ---------------- within-wave transpose via per-wave scratch ----------
    const int g   = lane >> 3;          // LU group 0..7
    const int s8  = lane & 7;
    const int m   = g & 1;              // 0 = up, 1 = dn
    const int bwl = g >> 1;             // batch-in-wave 0..3
    int batch = blockIdx.x * NB + wb0 + bwl;
    const bool valid = (batch < B);
    if (!valid) batch = B - 1;

    float* const sw = uni + wv * 1280;          // [2 batches][32 rows][20]
    float* const wr = sw + rowidx * 20 + (h << 3);
    float a0[16], a1[16];

    // pass A: write batches 0,1; LU-read for lanes 0..31
    {
        f32x4 t;
        t.lo = acc[0][0]; t.hi = acc[0][1];
        *reinterpret_cast<f32x4*>(wr + ((0 ^ rot) << 2)) = t;
        t.lo = acc[0][2]; t.hi = acc[0][3];
        *reinterpret_cast<f32x4*>(wr + ((1 ^ rot) << 2)) = t;
        t.lo = acc[1][0]; t.hi = acc[1][1];
        *reinterpret_cast<f32x4*>(wr + 640 + ((0 ^ rot) << 2)) = t;
        t.lo = acc[1][2]; t.hi = acc[1][3];
        *reinterpret_cast<f32x4*>(wr + 640 + ((1 ^ rot) << 2)) = t;
    }
    asm volatile("s_waitcnt lgkmcnt(0)" ::: "memory");
    __builtin_amdgcn_sched_barrier(0);
    if (lane < 32) {
        const float* r0 = sw + bwl * 640 + (m * 16 + s8) * 20;
        const float* r1 = r0 + 160;
        #pragma unroll
        for (int qq = 0; qq < 4; qq++) {
            f32x4 u0 = *reinterpret_cast<const f32x4*>(r0 + qq * 4);
            f32x4 u1 = *reinterpret_cast<const f32x4*>(r1 + qq * 4);
            a0[qq*4+0] = u0.x; a0[qq*4+1] = u0.y; a0[qq*4+2] = u0.z; a0[qq*4+3] = u0.w;
            a1[qq*4+0] = u1.x; a1[qq*4+1] = u1.y; a1[qq*4+2] = u1.z; a1[qq*4+3] = u1.w;
        }
    }
    asm volatile("s_waitcnt lgkmcnt(0)" ::: "memory");
    __builtin_amdgcn_sched_barrier(0);
    // pass B: overwrite with batches 2,3; LU-read for lanes 32..63
    {
        f32x4 t;
        t.lo = acc[2][0]; t.hi = acc[2][1];
        *reinterpret_cast<f32x4*>(wr + ((0 ^ rot) << 2)) = t;
        t.lo = acc[2][2]; t.hi = acc[2][3];
        *reinterpret_cast<f32x4*>(wr + ((1 ^ rot) << 2)) = t;
        t.lo = acc[3][0]; t.hi = acc[3][1];
        *reinterpret_cast<f32x4*>(wr + 640 + ((0 ^ rot) << 2)) = t;
        t.lo = acc[3][2]; t.hi = acc[3][3];
        *reinterpret_cast<f32x4*>(wr + 640 + ((1 ^ rot) << 2)) = t;
    }
    asm volatile("s_waitcnt lgkmcnt(0)" ::: "memory");
    __builtin_amdgcn_sched_barrier(0);
    if (lane >= 32) {
        const float* r0 = sw + (bwl - 2) * 640 + (m * 16 + s8) * 20;
        const float* r1 = r0 + 160;
        #pragma unroll
        for (int qq = 0; qq < 4; qq++) {
            f32x4 u0 = *reinterpret_cast<const f32x4*>(r0 + qq * 4);
            f32x4 u1 = *reinterpret_cast<const f32x4*>(r1 + qq * 4);
            a0[qq*4+0] = u0.x; a0[qq*4+1] = u0.y; a0[qq*4+2] = u0.z; a0[qq*4+3] = u0.w;
            a1[qq*4+0] = u1.x; a1[qq*4+1] = u1.y; a1[qq*4+2] = u1.z; a1[qq*4+3] = u1.w;
        }
    }

    // ---------------- LU, implicit partial pivoting (register rows) --------
    unsigned active = 0xffffu;
    int inv = 0;
    float myd0 = 1.f, myd1 = 1.f;

    #pragma unroll
    for (int k = 0; k < 16; k++) {
        const unsigned act0 = (active >> s8) & 1u;
        const unsigned act1 = (active >> (s8 + 8)) & 1u;
        float av = act0 ? fabsf(a0[k]) : -1.f;
        int idx = s8;
        {
            float av1 = act1 ? fabsf(a1[k]) : -1.f;
            if (av1 > av) { av = av1; idx = s8 + 8; }
        }
        #pragma unroll
        for (int d = 1; d < 8; d <<= 1) {
            float ov = __shfl_xor(av, d, 8);
            int   oi = __shfl_xor(idx, d, 8);
            if (ov > av || (ov == av && oi < idx)) { av = ov; idx = oi; }
        }
        const int p = idx;
        const int plane = p & 7;
        const bool phi = (p & 8) != 0;
        float psel = phi ? a1[k] : a0[k];
        const float pk = __shfl(psel, plane, 8);
        const float rcp = 1.0f / pk;

        if (s8 == p)     myd0 = pk;
        if (s8 + 8 == p) myd1 = pk;
        inv += __popc(active & ((1u << p) - 1u));
        active &= ~(1u << p);

        const float f0 = (act0 && s8 != p)       ? a0[k] * rcp : 0.f;
        const float f1 = (act1 && (s8 + 8) != p) ? a1[k] * rcp : 0.f;

        #pragma unroll
        for (int j = k + 1; j < 16; j++) {
            float sel = phi ? a1[j] : a0[j];
            float pv = __shfl(sel, plane, 8);
            a0[j] = fmaf(-f0, pv, a0[j]);
            a1[j] = fmaf(-f1, pv, a1[j]);
        }
    }

    float ld = logf(fabsf(myd0)) + logf(fabsf(myd1));
    int ng = ((myd0 < 0.f) ? 1 : 0) + ((myd1 < 0.f) ? 1 : 0);
    #pragma unroll
    for (int d = 1; d < 8; d <<= 1) {
        ld += __shfl_xor(ld, d, 8);
        ng += __shfl_xor(ng, d, 8);
    }
    const int neg = (ng + inv) & 1;

    const float ld_o  = __shfl_xor(ld, 8, 16);
    const int   neg_o = __shfl_xor(neg, 8, 16);

    if ((lane & 15) == 0 && valid) {
        out[batch]     = ld + ld_o;                                      // re plane
        out[B + batch] = 3.14159265358979323846f * (float)(neg + neg_o); // im plane
    }
}

extern "C" void kernel_launch(void* const* d_in, const int* in_sizes, int n_in,
                              void* d_out, int out_size, void* d_ws, size_t ws_size,
                              hipStream_t stream) {
    const int* nocc = (const int*)d_in[0];
    const float* W  = (const float*)d_in[1];
    float* out = (float*)d_out;
    const int B = in_sizes[0] / 128;                 // 65536
    const int blocks = (B + NB - 1) / NB;            // 2048
    backflow_kernel<<<blocks, 512, 0, stream>>>(nocc, W, out, B);
}